// Round 2
// baseline (887.964 us; speedup 1.0000x reference)
//
#include <hip/hip_runtime.h>
#include <cstdint>
#include <cstddef>

#define IN_F  4096
#define OUT_F 16384
#define NROWS 8192   // 2*4096 tokens

typedef __attribute__((ext_vector_type(4)))  int int32x4;
typedef __attribute__((ext_vector_type(16))) int int32x16;

// ---------------------------------------------------------------------------
// async global->LDS, 16B per lane (LDS dest = wave-uniform base + lane*16)
// ---------------------------------------------------------------------------
__device__ __forceinline__ void gload_lds16(const void* g, void* s) {
    __builtin_amdgcn_global_load_lds((const __attribute__((address_space(1))) void*)g,
                                     (__attribute__((address_space(3))) void*)s,
                                     16, 0, 0);
}

// ---------------------------------------------------------------------------
// Kernel 1: weight [K=4096][N=16384] *int32* (harness pushes int8 as int)
//           -> narrow to i8 + transpose -> Wt [N][K] int8
// 64x64 tiles via LDS; wave reads 256B contiguous per row; 16B writes.
// ---------------------------------------------------------------------------
__global__ __launch_bounds__(256) void transpose_kernel(const int* __restrict__ w,
                                                        int8_t* __restrict__ wt) {
    __shared__ uint8_t tile[64][68];   // +4 pad breaks bank conflicts on column reads
    const int t  = threadIdx.x;
    const int nb = blockIdx.x * 64;    // n tile origin
    const int kb = blockIdx.y * 64;    // k tile origin

    // load + narrow: pass p handles k-rows p*16 + (t>>4); 16 threads/row * 4 ints
#pragma unroll
    for (int p = 0; p < 4; ++p) {
        const int r = p * 16 + (t >> 4);
        const int c = t & 15;
        int4 u = *reinterpret_cast<const int4*>(w + (size_t)(kb + r) * OUT_F + nb + c * 4);
        uint32_t packed = (uint32_t)(u.x & 255)
                        | ((uint32_t)(u.y & 255) << 8)
                        | ((uint32_t)(u.z & 255) << 16)
                        | ((uint32_t)(u.w & 255) << 24);
        *reinterpret_cast<uint32_t*>(&tile[r][c * 4]) = packed;
    }
    __syncthreads();

    // transpose write: output row rn (n index), 16 k-bytes per thread
    const int rn = t >> 2;             // 0..63
    const int q  = t & 3;              // 16B chunk 0..3
    uint4 o;
    uint32_t* op = reinterpret_cast<uint32_t*>(&o);
#pragma unroll
    for (int j = 0; j < 4; ++j) {
        const int kk = q * 16 + j * 4;
        op[j] = (uint32_t)tile[kk + 0][rn]
              | ((uint32_t)tile[kk + 1][rn] << 8)
              | ((uint32_t)tile[kk + 2][rn] << 16)
              | ((uint32_t)tile[kk + 3][rn] << 24);
    }
    *reinterpret_cast<uint4*>(wt + (size_t)(nb + rn) * IN_F + kb + q * 16) = o;
}

// ---------------------------------------------------------------------------
// Kernel 2: per-row dynamic quantization
// x [8192][4096] f32 -> xq [8192][4096] i8, xs [8192] f32
// ---------------------------------------------------------------------------
__global__ __launch_bounds__(256) void quant_kernel(const float* __restrict__ x,
                                                    int8_t* __restrict__ xq,
                                                    float* __restrict__ xs) {
    const int row = blockIdx.x;
    const int t   = threadIdx.x;
    const float* xr = x + (size_t)row * IN_F;

    float4 v[4];
    float am = 0.0f;
#pragma unroll
    for (int j = 0; j < 4; ++j) {
        v[j] = reinterpret_cast<const float4*>(xr)[j * 256 + t];
        am = fmaxf(am, fmaxf(fmaxf(fabsf(v[j].x), fabsf(v[j].y)),
                             fmaxf(fabsf(v[j].z), fabsf(v[j].w))));
    }
#pragma unroll
    for (int off = 32; off; off >>= 1) am = fmaxf(am, __shfl_xor(am, off));

    __shared__ float red[4];
    if ((t & 63) == 0) red[t >> 6] = am;
    __syncthreads();
    am = fmaxf(fmaxf(red[0], red[1]), fmaxf(red[2], red[3]));

    // match reference: scale = max(absmax/127, 1e-12); q = clip(round(x/scale))
    const float scale = fmaxf(am / 127.0f, 1e-12f);
    if (t == 0) xs[row] = scale;

    uint32_t* q = reinterpret_cast<uint32_t*>(xq + (size_t)row * IN_F);
#pragma unroll
    for (int j = 0; j < 4; ++j) {
        float r0 = fminf(127.f, fmaxf(-128.f, rintf(v[j].x / scale)));
        float r1 = fminf(127.f, fmaxf(-128.f, rintf(v[j].y / scale)));
        float r2 = fminf(127.f, fmaxf(-128.f, rintf(v[j].z / scale)));
        float r3 = fminf(127.f, fmaxf(-128.f, rintf(v[j].w / scale)));
        q[j * 256 + t] = ((uint32_t)((int)r0 & 255))
                       | ((uint32_t)((int)r1 & 255) << 8)
                       | ((uint32_t)((int)r2 & 255) << 16)
                       | ((uint32_t)((int)r3 & 255) << 24);
    }
}

// ---------------------------------------------------------------------------
// Kernel 3: int8 GEMM  C[m][n] = sum_k xq[m][k] * Wt[n][k]
// 128x128 tile, BK=128 bytes, 4 waves * (2x2 of mfma_i32_32x32x32_i8).
// global_load_lds staging with pre-swizzled source; XOR swizzle
// (chunk ^= row&7) kills ds_read_b128 bank conflicts.
// ---------------------------------------------------------------------------
#define BM 128
#define BN 128
#define BK 128

__global__ __launch_bounds__(256) void gemm_kernel(const int8_t* __restrict__ xq,
                                                   const int8_t* __restrict__ wt,
                                                   const float* __restrict__ xs,
                                                   const float* __restrict__ wsc,
                                                   const float* __restrict__ bias,
                                                   float* __restrict__ out) {
    __shared__ int8_t la[BM * BK];   // 16 KB (swizzled layout)
    __shared__ int8_t lb[BN * BK];   // 16 KB

    const int t    = threadIdx.x;
    const int lane = t & 63;
    const int wid  = t >> 6;

    // XCD-aware bijective swizzle: 8192 blocks, 8 XCDs, 8192 % 8 == 0
    int bid = blockIdx.x;
    bid = (bid & 7) * (8192 / 8) + (bid >> 3);
    const int mt = bid >> 7;      // 0..63
    const int nt = bid & 127;     // 0..127
    const size_t bm = (size_t)mt * BM;
    const size_t bn = (size_t)nt * BN;

    // ---- staging source (inverse-swizzled global address, G21) ----
    // linear LDS offset o = p*4096 + t*16 ; row = o>>7 ; chunk = ((o>>4)&7) ^ ((o>>7)&7)
    const int srow = t >> 3;                        // 0..31 (per pass, +p*32)
    const int sch  = (t & 7) ^ ((t >> 3) & 7);      // swizzled source chunk
    const uint8_t* aSrc = (const uint8_t*)xq + (bm + srow) * (size_t)IN_F + sch * 16;
    const uint8_t* bSrc = (const uint8_t*)wt + (bn + srow) * (size_t)IN_F + sch * 16;

    // ---- fragment LDS byte offsets (swizzled read, K-loop invariant) ----
    const int wm = wid >> 1, wn = wid & 1;          // wave tile: rows wm*64, cols wn*64
    int offA[2][4], offB[2][4];
#pragma unroll
    for (int tr = 0; tr < 2; ++tr) {
        const int ra = wm * 64 + tr * 32 + (lane & 31);
        const int rb = wn * 64 + tr * 32 + (lane & 31);
#pragma unroll
        for (int ks = 0; ks < 4; ++ks) {
            const int ch = ks * 2 + (lane >> 5);
            offA[tr][ks] = ra * BK + ((ch ^ (ra & 7)) << 4);
            offB[tr][ks] = rb * BK + ((ch ^ (rb & 7)) << 4);
        }
    }

    int32x16 acc[2][2] = {};

    for (int kt = 0; kt < IN_F; kt += BK) {
#pragma unroll
        for (int p = 0; p < 4; ++p) {
            gload_lds16(aSrc + (size_t)kt + (size_t)p * 32 * IN_F, la + p * 4096 + wid * 1024);
            gload_lds16(bSrc + (size_t)kt + (size_t)p * 32 * IN_F, lb + p * 4096 + wid * 1024);
        }
        __syncthreads();   // compiler drains vmcnt before barrier

#pragma unroll
        for (int ks = 0; ks < 4; ++ks) {
            int32x4 a0 = *reinterpret_cast<const int32x4*>(la + offA[0][ks]);
            int32x4 a1 = *reinterpret_cast<const int32x4*>(la + offA[1][ks]);
            int32x4 b0 = *reinterpret_cast<const int32x4*>(lb + offB[0][ks]);
            int32x4 b1 = *reinterpret_cast<const int32x4*>(lb + offB[1][ks]);
            acc[0][0] = __builtin_amdgcn_mfma_i32_32x32x32_i8(a0, b0, acc[0][0], 0, 0, 0);
            acc[0][1] = __builtin_amdgcn_mfma_i32_32x32x32_i8(a0, b1, acc[0][1], 0, 0, 0);
            acc[1][0] = __builtin_amdgcn_mfma_i32_32x32x32_i8(a1, b0, acc[1][0], 0, 0, 0);
            acc[1][1] = __builtin_amdgcn_mfma_i32_32x32x32_i8(a1, b1, acc[1][1], 0, 0, 0);
        }
        __syncthreads();
    }

    // ---- epilogue: dequant + bias ----
    // C/D layout (32x32): col = lane&31, row = (g&3) + 8*(g>>2) + 4*(lane>>5)
    const int row0 = (int)bm + wm * 64;
    const int col0 = (int)bn + wn * 64;
#pragma unroll
    for (int tc = 0; tc < 2; ++tc) {
        const int n   = col0 + tc * 32 + (lane & 31);
        const float wn_s = wsc[n];
        const float bn_s = bias[n];
#pragma unroll
        for (int tr = 0; tr < 2; ++tr) {
            const int rbase = row0 + tr * 32 + 4 * (lane >> 5);
#pragma unroll
            for (int g = 0; g < 16; ++g) {
                const int m = rbase + (g & 3) + 8 * (g >> 2);
                out[(size_t)m * OUT_F + n] = (float)acc[tr][tc][g] * xs[m] * wn_s + bn_s;
            }
        }
    }
}

// ---------------------------------------------------------------------------
extern "C" void kernel_launch(void* const* d_in, const int* in_sizes, int n_in,
                              void* d_out, int out_size, void* d_ws, size_t ws_size,
                              hipStream_t stream) {
    const float* x    = (const float*)d_in[0];
    const int*   wq   = (const int*)d_in[1];     // int8 pushed as int32 [4096][16384]
    const float* wsc  = (const float*)d_in[2];   // [16384]
    const float* bias = (const float*)d_in[3];   // [16384]
    float* out = (float*)d_out;

    uint8_t* ws = (uint8_t*)d_ws;
    int8_t* wt = (int8_t*)ws;                                          // 64 MiB
    int8_t* xq = (int8_t*)(ws + (size_t)IN_F * OUT_F);                 // 32 MiB
    float*  xs = (float*)(ws + (size_t)IN_F * OUT_F + (size_t)NROWS * IN_F);

    transpose_kernel<<<dim3(OUT_F / 64, IN_F / 64), 256, 0, stream>>>(wq, wt);
    quant_kernel<<<NROWS, 256, 0, stream>>>(x, xq, xs);
    gemm_kernel<<<(NROWS / BM) * (OUT_F / BN), 256, 0, stream>>>(xq, wt, xs, wsc, bias, out);
}

// Round 3
// 693.476 us; speedup vs baseline: 1.2805x; 1.2805x over previous
//
#include <hip/hip_runtime.h>
#include <cstdint>
#include <cstddef>

#define IN_F  4096
#define OUT_F 16384
#define NROWS 8192   // 2*4096 tokens
#define NKT   64     // K-tiles of 64 bytes

typedef __attribute__((ext_vector_type(4)))  int int32x4;
typedef __attribute__((ext_vector_type(16))) int int32x16;

// async global->LDS, 16B/lane (dest = wave-uniform base, HW adds lane*16)
__device__ __forceinline__ void gload_lds16(const void* g, void* s) {
    __builtin_amdgcn_global_load_lds((const __attribute__((address_space(1))) void*)g,
                                     (__attribute__((address_space(3))) void*)s,
                                     16, 0, 0);
}

// ---------------------------------------------------------------------------
// Layouts (fragment-major, shared by producers and GEMM staging):
//   xqS: [mtile 32][kt 64][c 4][row 256][16B]   c = ksub*2+kh, k = kt*64+c*16..+16
//   wtS: [ntile 64][kt 64][c 4][col 256][16B]
// GEMM stages 8KB halves contiguously (src + tid*16 -> linear LDS), and the
// MFMA fragment reads are lane-contiguous 16B -> zero LDS bank conflicts.
// ---------------------------------------------------------------------------

// Kernel 1: weight [K=4096][N=16384] int32 -> wtS (narrow + transpose + tile)
__global__ __launch_bounds__(256) void transpose_kernel(const int* __restrict__ w,
                                                        uint8_t* __restrict__ wtS) {
    __shared__ uint8_t tile[64][68];
    const int t  = threadIdx.x;
    const int nb = blockIdx.x * 64;
    const int kt = blockIdx.y;          // K-tile = 64 k-rows
    const int kb = kt * 64;

#pragma unroll
    for (int p = 0; p < 4; ++p) {
        const int r = p * 16 + (t >> 4);
        const int c4 = t & 15;
        int4 u = *reinterpret_cast<const int4*>(w + (size_t)(kb + r) * OUT_F + nb + c4 * 4);
        uint32_t packed = (uint32_t)(u.x & 255) | ((uint32_t)(u.y & 255) << 8)
                        | ((uint32_t)(u.z & 255) << 16) | ((uint32_t)(u.w & 255) << 24);
        *reinterpret_cast<uint32_t*>(&tile[r][c4 * 4]) = packed;
    }
    __syncthreads();

    const int col = t >> 2;             // 0..63
    const int c   = t & 3;              // ksub*2+kh
    uint4 o;
    uint32_t* op = reinterpret_cast<uint32_t*>(&o);
#pragma unroll
    for (int j = 0; j < 4; ++j) {
        const int kk = c * 16 + j * 4;
        op[j] = (uint32_t)tile[kk][col] | ((uint32_t)tile[kk + 1][col] << 8)
              | ((uint32_t)tile[kk + 2][col] << 16) | ((uint32_t)tile[kk + 3][col] << 24);
    }
    const int ntile = nb >> 8;
    const int colg  = (nb & 255) + col;
    *reinterpret_cast<uint4*>(wtS + (((size_t)ntile * NKT + kt) * 4 + c) * 4096 + colg * 16) = o;
}

// Kernel 2: per-row dynamic quant -> xqS (fragment-major) + xs
// block = 8 rows; wave w: rows 2w (lanes 0-31) / 2w+1 (lanes 32-63)
__global__ __launch_bounds__(256) void quant_kernel(const float* __restrict__ x,
                                                    uint8_t* __restrict__ xqS,
                                                    float* __restrict__ xs) {
    const int t = threadIdx.x;
    const int w = t >> 6, l = t & 63;
    const int half = l >> 5, lh = l & 31;
    const int m = blockIdx.x * 8 + w * 2 + half;
    const float* xr = x + (size_t)m * IN_F;

    // pass 1: coalesced absmax
    float am = 0.0f;
#pragma unroll 8
    for (int jj = 0; jj < 32; ++jj) {
        float4 v = reinterpret_cast<const float4*>(xr)[jj * 32 + lh];
        am = fmaxf(am, fmaxf(fmaxf(fabsf(v.x), fabsf(v.y)),
                             fmaxf(fabsf(v.z), fabsf(v.w))));
    }
#pragma unroll
    for (int off = 16; off; off >>= 1) am = fmaxf(am, __shfl_xor(am, off));

    const float scale = fmaxf(am / 127.0f, 1e-12f);
    if (lh == 0) xs[m] = scale;

    // pass 2: per-lane-contiguous 16-value chunks (L2/L3-hot re-read)
    const int mtile = m >> 8, mrow = m & 255;
    uint8_t* ob = xqS + (size_t)mtile * (NKT * 16384) + (size_t)mrow * 16;
#pragma unroll
    for (int j = 0; j < 8; ++j) {
        const int k0 = lh * 128 + j * 16;
        const float4* vp = reinterpret_cast<const float4*>(xr + k0);
        uint4 pk;
        uint32_t* pp = reinterpret_cast<uint32_t*>(&pk);
#pragma unroll
        for (int q = 0; q < 4; ++q) {
            float4 v = vp[q];
            float r0 = fminf(127.f, fmaxf(-128.f, rintf(v.x / scale)));
            float r1 = fminf(127.f, fmaxf(-128.f, rintf(v.y / scale)));
            float r2 = fminf(127.f, fmaxf(-128.f, rintf(v.z / scale)));
            float r3 = fminf(127.f, fmaxf(-128.f, rintf(v.w / scale)));
            pp[q] = ((uint32_t)((int)r0 & 255)) | ((uint32_t)((int)r1 & 255) << 8)
                  | ((uint32_t)((int)r2 & 255) << 16) | ((uint32_t)((int)r3 & 255) << 24);
        }
        const int ktk = k0 >> 6;
        const int c   = (k0 >> 4) & 3;
        *reinterpret_cast<uint4*>(ob + ((size_t)ktk * 4 + c) * 4096) = pk;
    }
}

// ---------------------------------------------------------------------------
// Kernel 3: int8 GEMM, 256x256 tile, BK=64B, 8 waves (2Mx4N), quad-buffered
// LDS (128KB dynamic), depth-2 prefetch, counted vmcnt(4), setprio on MFMA.
// ---------------------------------------------------------------------------
__global__ __launch_bounds__(512, 2) void gemm_kernel(const uint8_t* __restrict__ xqS,
                                                      const uint8_t* __restrict__ wtS,
                                                      const float* __restrict__ xs,
                                                      const float* __restrict__ wsc,
                                                      const float* __restrict__ bias,
                                                      float* __restrict__ out) {
    extern __shared__ uint8_t lds[];
    uint8_t* ldsA = lds;            // 4 bufs * 16KB
    uint8_t* ldsB = lds + 65536;    // 4 bufs * 16KB

    const int t    = threadIdx.x;
    const int lane = t & 63;
    const int wid  = t >> 6;
    const int wm   = wid >> 2, wn = wid & 3;   // wave tile: 128 rows x 64 cols

    // XCD-aware bijective swizzle: 2048 blocks, 2048 % 8 == 0
    int bid = blockIdx.x;
    bid = (bid & 7) * 256 + (bid >> 3);
    const int mt = bid >> 6;      // 0..31
    const int nt = bid & 63;      // 0..63

    const uint8_t* aBase = xqS + (size_t)mt * (NKT * 16384);
    const uint8_t* bBase = wtS + (size_t)nt * (NKT * 16384);
    const int t16  = t * 16;
    const int wofs = wid * 1024;                 // wave-uniform LDS chunk

    // fragment read bases (lane-contiguous per 32-lane half: conflict-free)
    const int aRd0 = (lane >> 5) * 4096 + wm * 2048 + (lane & 31) * 16;
    const int bRd0 = (lane >> 5) * 4096 + wn * 1024 + (lane & 31) * 16;

    int32x16 acc[4][2] = {};

    // prologue: stage K-tiles 0,1
#pragma unroll
    for (int tt = 0; tt < 2; ++tt)
#pragma unroll
        for (int L = 0; L < 2; ++L) {
            gload_lds16(aBase + tt * 16384 + L * 8192 + t16, ldsA + tt * 16384 + L * 8192 + wofs);
            gload_lds16(bBase + tt * 16384 + L * 8192 + t16, ldsB + tt * 16384 + L * 8192 + wofs);
        }
    asm volatile("s_waitcnt vmcnt(4)" ::: "memory");   // tile0 landed
    __builtin_amdgcn_s_barrier();

    for (int kt = 0; kt < NKT; ++kt) {
        const int q  = (kt & 3) * 16384;
        const int q2 = ((kt + 2) & 3) * 16384;
        const size_t src2 = (size_t)(kt + 2) * 16384;
        const bool st = (kt < NKT - 2);
#pragma unroll
        for (int s = 0; s < 2; ++s) {
            int32x4 af[4], bf[2];
            const uint8_t* ap = ldsA + q + s * 8192 + aRd0;
            const uint8_t* bp = ldsB + q + s * 8192 + bRd0;
#pragma unroll
            for (int mr = 0; mr < 4; ++mr)
                af[mr] = *reinterpret_cast<const int32x4*>(ap + mr * 512);
#pragma unroll
            for (int nr = 0; nr < 2; ++nr)
                bf[nr] = *reinterpret_cast<const int32x4*>(bp + nr * 512);

            if (st) {   // stage half s of K-tile kt+2
                gload_lds16(aBase + src2 + s * 8192 + t16, ldsA + q2 + s * 8192 + wofs);
                gload_lds16(bBase + src2 + s * 8192 + t16, ldsB + q2 + s * 8192 + wofs);
            }
            if (s == 1) {   // once per K-tile: next tile's 4 loads retired
                if (kt < NKT - 2)       asm volatile("s_waitcnt vmcnt(4)" ::: "memory");
                else if (kt == NKT - 2) asm volatile("s_waitcnt vmcnt(0)" ::: "memory");
            }
            __builtin_amdgcn_s_barrier();
            __builtin_amdgcn_s_setprio(1);
#pragma unroll
            for (int mr = 0; mr < 4; ++mr)
#pragma unroll
                for (int nr = 0; nr < 2; ++nr)
                    acc[mr][nr] = __builtin_amdgcn_mfma_i32_32x32x32_i8(af[mr], bf[nr], acc[mr][nr], 0, 0, 0);
            __builtin_amdgcn_s_setprio(0);
            __builtin_amdgcn_s_barrier();
        }
    }

    // epilogue: C/D 32x32 layout: col = lane&31, row = (g&3)+8*(g>>2)+4*(lane>>5)
    const int row0 = mt * 256 + wm * 128;
    const int col0 = nt * 256 + wn * 64;
#pragma unroll
    for (int mr = 0; mr < 4; ++mr) {
        const int rbase = row0 + mr * 32 + 4 * (lane >> 5);
        float xsv[16];
#pragma unroll
        for (int g = 0; g < 16; ++g)
            xsv[g] = xs[rbase + (g & 3) + 8 * (g >> 2)];
#pragma unroll
        for (int nr = 0; nr < 2; ++nr) {
            const int n = col0 + nr * 32 + (lane & 31);
            const float ws_n = wsc[n];
            const float b_n  = bias[n];
#pragma unroll
            for (int g = 0; g < 16; ++g) {
                const int m = rbase + (g & 3) + 8 * (g >> 2);
                out[(size_t)m * OUT_F + n] = (float)acc[mr][nr][g] * xsv[g] * ws_n + b_n;
            }
        }
    }
}

// ---------------------------------------------------------------------------
extern "C" void kernel_launch(void* const* d_in, const int* in_sizes, int n_in,
                              void* d_out, int out_size, void* d_ws, size_t ws_size,
                              hipStream_t stream) {
    const float* x    = (const float*)d_in[0];
    const int*   wq   = (const int*)d_in[1];     // int8 pushed as int32 [4096][16384]
    const float* wsc  = (const float*)d_in[2];
    const float* bias = (const float*)d_in[3];
    float* out = (float*)d_out;

    uint8_t* ws  = (uint8_t*)d_ws;
    uint8_t* wtS = ws;                                               // 64 MiB
    uint8_t* xqS = ws + (size_t)IN_F * OUT_F;                        // 32 MiB
    float*   xs  = (float*)(ws + (size_t)IN_F * OUT_F + (size_t)NROWS * IN_F);

    (void)hipFuncSetAttribute((const void*)gemm_kernel,
                              hipFuncAttributeMaxDynamicSharedMemorySize, 131072);

    transpose_kernel<<<dim3(OUT_F / 64, IN_F / 64), 256, 0, stream>>>(wq, wtS);
    quant_kernel<<<NROWS / 8, 256, 0, stream>>>(x, xqS, xs);
    gemm_kernel<<<(NROWS / 256) * (OUT_F / 256), 512, 131072, stream>>>(xqS, wtS, xs, wsc, bias, out);
}